// Round 1
// baseline (184.152 us; speedup 1.0000x reference)
//
#include <hip/hip_runtime.h>
#include <math.h>

#define B_   32
#define C_   64
#define H_   224
#define W_   224
#define HW_  (H_*W_)          // 50176
#define HW4_ (HW_/4)          // 12544
#define G_   36
#define CHUNKS_ 28
#define PIX_PER_CHUNK_ (HW_/CHUNKS_)          // 1792 = 7*256
#define PIX_PER_THREAD_ (PIX_PER_CHUNK_/256)  // 7

typedef float f4v __attribute__((ext_vector_type(4)));

// ---------------- kernel 1: channel mean (nt streaming reads) ----------------
__global__ __launch_bounds__(256) void k_mean(const float* __restrict__ x,
                                              float* __restrict__ a,
                                              unsigned* __restrict__ counter) {
    if (blockIdx.x == 0 && threadIdx.x == 0) *counter = 0u;  // ticket init (stream-ordered before k_sums)
    int b = blockIdx.x / 49;                      // 49 blocks per image (49*256 = 12544 float4)
    int i = (blockIdx.x % 49) * 256 + threadIdx.x;
    const f4v* x4 = reinterpret_cast<const f4v*>(x) + (size_t)b * C_ * HW4_ + i;
    f4v s = {0.f, 0.f, 0.f, 0.f};
    #pragma unroll 16
    for (int c = 0; c < C_; ++c) {
        f4v v = __builtin_nontemporal_load(x4 + (size_t)c * HW4_);  // read-once: bypass cache retention
        s += v;
    }
    s *= (1.0f / 64.0f);
    reinterpret_cast<f4v*>(a)[(size_t)b * HW4_ + i] = s;            // normal store: a is reused, keep cached
}

// neighbor gather for pixel p of image ab; nn[9] per GLCM channel order
__device__ __forceinline__ void gather9(const float* __restrict__ ab, int p, float* nn) {
    int h = p / W_, w = p % W_;
    int hm = h > 0 ? h - 1 : 0, hp = h < H_-1 ? h + 1 : H_-1;
    int wm = w > 0 ? w - 1 : 0, wp = w < W_-1 ? w + 1 : W_-1;
    nn[0] = ab[h*W_ + w];
    nn[1] = ab[h*W_ + wp];
    nn[2] = ab[hp*W_ + w];
    nn[3] = ab[hp*W_ + wp];
    nn[4] = ab[h*W_ + wm];
    nn[5] = ab[hm*W_ + w];
    nn[6] = nn[3];                  // left(up) == up(left)
    nn[7] = ab[hm*W_ + wp];
    nn[8] = ab[hm*W_ + wm];
}

#define PAIR_LISTS \
    const int P0[G_] = {0,0,0,0,0,0,0,0, 1,1,1,1,1,1,1, 2,2,2,2,2,2, 3,3,3,3,3, 4,4,4,4, 5,5,5, 6,6, 7}; \
    const int P1[G_] = {1,2,3,4,5,6,7,8, 2,3,4,5,6,7,8, 3,4,5,6,7,8, 4,5,6,7,8, 5,6,7,8, 6,7,8, 7,8, 8};

// ---------------- kernel 2: per-(b,g) partial sums + fused attention (last block) ----------------
__global__ __launch_bounds__(256) void k_sums_att(
    const float* __restrict__ a,
    const float* __restrict__ gw,
    const float* __restrict__ bng_g, const float* __restrict__ bng_b,
    const float* __restrict__ bng_m, const float* __restrict__ bng_v,
    const float* __restrict__ bn1_g, const float* __restrict__ bn1_b,
    const float* __restrict__ bn1_m, const float* __restrict__ bn1_v,
    const float* __restrict__ w1, const float* __restrict__ ca_w1,
    const float* __restrict__ ca_w2,
    float* __restrict__ partial, float* __restrict__ vout,
    float* __restrict__ cout, unsigned* __restrict__ counter)
{
    PAIR_LISTS
    int b = blockIdx.x / CHUNKS_;
    int chunk = blockIdx.x % CHUNKS_;
    int t = threadIdx.x;
    __shared__ float sA0[G_], sA1[G_], sB[G_];
    __shared__ float red[4 * G_];
    __shared__ unsigned sticket;
    // fold BN-g constants per block (was k_prep)
    if (t < G_) {
        float sg = bng_g[t] / sqrtf(bng_v[t] + 1e-5f);
        sA0[t] = gw[2*t+0] * sg;
        sA1[t] = gw[2*t+1] * sg;
        sB[t]  = bng_b[t] - bng_m[t] * sg;
    }
    __syncthreads();
    const float* ab = a + (size_t)b * HW_;
    float acc[G_];
    #pragma unroll
    for (int g = 0; g < G_; ++g) acc[g] = 0.f;
    #pragma unroll 2
    for (int k = 0; k < PIX_PER_THREAD_; ++k) {
        int p = chunk * PIX_PER_CHUNK_ + k * 256 + t;
        float nn[9];
        gather9(ab, p, nn);
        #pragma unroll
        for (int g = 0; g < G_; ++g) {
            float y = fmaf(sA0[g], nn[P0[g]], fmaf(sA1[g], nn[P1[g]], sB[g]));
            acc[g] += fmaxf(y, 0.f);
        }
    }
    int lane = t & 63, wave = t >> 6;
    #pragma unroll
    for (int g = 0; g < G_; ++g) {
        float v = acc[g];
        v += __shfl_down(v, 32);
        v += __shfl_down(v, 16);
        v += __shfl_down(v, 8);
        v += __shfl_down(v, 4);
        v += __shfl_down(v, 2);
        v += __shfl_down(v, 1);
        if (lane == 0) red[wave * G_ + g] = v;
    }
    __syncthreads();
    if (t < G_) {
        partial[(size_t)(b * CHUNKS_ + chunk) * G_ + t] =
            red[t] + red[G_+t] + red[2*G_+t] + red[3*G_+t];
    }

    // ---- last-block-done ticket (device scope; per-XCD L2s are not coherent -> agent fences) ----
    __threadfence();                 // release partial[] to agent scope
    __syncthreads();                 // order t0's atomic after all lanes' stores+fences
    if (t == 0)
        sticket = __hip_atomic_fetch_add(counter, 1u, __ATOMIC_ACQ_REL, __HIP_MEMORY_SCOPE_AGENT);
    __syncthreads();
    if (sticket != (unsigned)(gridDim.x - 1)) return;

    // ---------- attention MLP phase (one block, 256 threads, data-parallel over b*g) ----------
    __threadfence();                 // acquire: see all partial[] writes
    __shared__ float ss1[G_], sb1[G_];
    __shared__ float meanr[B_ * G_], pooledv[B_ * G_], attv[B_ * G_];
    __shared__ float hidv[B_ * (G_/2)];
    if (t < G_) {
        float s1 = bn1_g[t] / sqrtf(bn1_v[t] + 1e-5f);
        ss1[t] = s1;
        sb1[t] = bn1_b[t] - bn1_m[t] * s1;
    }
    __syncthreads();
    for (int i = t; i < B_ * G_; i += 256) {
        int bb = i / G_, g = i - bb * G_;
        float s = 0.f;
        for (int j = 0; j < CHUNKS_; ++j) s += partial[(size_t)(bb * CHUNKS_ + j) * G_ + g];
        meanr[i] = s * (1.0f / (float)HW_);
    }
    __syncthreads();
    for (int i = t; i < B_ * G_; i += 256) {
        int bb = i / G_, o = i - bb * G_;
        float s = 0.f;
        #pragma unroll
        for (int g = 0; g < G_; ++g) s += w1[o*G_ + g] * meanr[bb*G_ + g];
        pooledv[i] = fmaf(s, ss1[o], sb1[o]);
    }
    __syncthreads();
    for (int i = t; i < B_ * (G_/2); i += 256) {
        int bb = i / (G_/2), k = i - bb * (G_/2);
        float s = 0.f;
        #pragma unroll
        for (int o = 0; o < G_; ++o) s += pooledv[bb*G_ + o] * ca_w1[k*G_ + o];
        hidv[i] = fmaxf(s, 0.f);
    }
    __syncthreads();
    for (int i = t; i < B_ * G_; i += 256) {
        int bb = i / G_, g = i - bb * G_;
        float s = 0.f;
        #pragma unroll
        for (int k = 0; k < G_/2; ++k) s += hidv[bb*(G_/2) + k] * ca_w2[g*(G_/2) + k];
        attv[i] = 1.0f / (1.0f + expf(-s));
    }
    __syncthreads();
    for (int i = t; i < B_ * G_; i += 256) {
        int bb = i / G_, g = i - bb * G_;
        float s = 0.f;
        #pragma unroll
        for (int o = 0; o < G_; ++o) s += attv[bb*G_ + o] * ss1[o] * w1[o*G_ + g];
        vout[i] = s;
    }
    for (int i = t; i < B_; i += 256) {
        float s = 0.f;
        #pragma unroll
        for (int o = 0; o < G_; ++o) s += attv[i*G_ + o] * sb1[o];
        cout[i] = s;
    }
    if (t == 0) *counter = 0u;       // self-reset: idempotent across graph replays
}

// ---------------- kernel 3: final output ----------------
__global__ __launch_bounds__(256) void k_out(const float* __restrict__ a,
                                             const float* __restrict__ gw,
                                             const float* __restrict__ bng_g, const float* __restrict__ bng_b,
                                             const float* __restrict__ bng_m, const float* __restrict__ bng_v,
                                             const float* __restrict__ v,
                                             const float* __restrict__ cvals,
                                             float* __restrict__ out) {
    PAIR_LISTS
    int b = blockIdx.x / CHUNKS_;
    int chunk = blockIdx.x % CHUNKS_;
    int t = threadIdx.x;
    __shared__ float sA0[G_], sA1[G_], sB[G_], sV[G_];
    __shared__ float sC;
    if (t < G_) {
        float sg = bng_g[t] / sqrtf(bng_v[t] + 1e-5f);
        sA0[t] = gw[2*t+0] * sg;
        sA1[t] = gw[2*t+1] * sg;
        sB[t]  = bng_b[t] - bng_m[t] * sg;
        sV[t]  = v[b*G_ + t];
    }
    if (t == 63) sC = cvals[b];
    __syncthreads();
    const float* ab = a + (size_t)b * HW_;
    float* ob = out + (size_t)b * HW_;
    #pragma unroll 2
    for (int k = 0; k < PIX_PER_THREAD_; ++k) {
        int p = chunk * PIX_PER_CHUNK_ + k * 256 + t;
        float nn[9];
        gather9(ab, p, nn);
        float s = sC;
        #pragma unroll
        for (int g = 0; g < G_; ++g) {
            float y = fmaf(sA0[g], nn[P0[g]], fmaf(sA1[g], nn[P1[g]], sB[g]));
            s = fmaf(fmaxf(y, 0.f), sV[g], s);
        }
        ob[p] = 1.0f / (1.0f + expf(-s));
    }
}

extern "C" void kernel_launch(void* const* d_in, const int* in_sizes, int n_in,
                              void* d_out, int out_size, void* d_ws, size_t ws_size,
                              hipStream_t stream) {
    const float* x     = (const float*)d_in[0];
    const float* gw    = (const float*)d_in[1];
    const float* w1    = (const float*)d_in[2];
    const float* ca_w1 = (const float*)d_in[3];
    const float* ca_w2 = (const float*)d_in[4];
    const float* bng_g = (const float*)d_in[5];
    const float* bng_b = (const float*)d_in[6];
    const float* bng_m = (const float*)d_in[7];
    const float* bng_v = (const float*)d_in[8];
    const float* bn1_g = (const float*)d_in[9];
    const float* bn1_b = (const float*)d_in[10];
    const float* bn1_m = (const float*)d_in[11];
    const float* bn1_v = (const float*)d_in[12];

    float* ws      = (float*)d_ws;
    float* a       = ws;                                   // 32*50176 floats
    float* partial = a + (size_t)B_ * HW_;                 // 32*28*36 floats
    float* v       = partial + (size_t)B_ * CHUNKS_ * G_;  // 32*36
    float* cvals   = v + B_ * G_;                          // 32
    unsigned* counter = (unsigned*)(cvals + B_);           // 1

    k_mean<<<B_ * 49, 256, 0, stream>>>(x, a, counter);
    k_sums_att<<<B_ * CHUNKS_, 256, 0, stream>>>(a, gw,
        bng_g, bng_b, bng_m, bng_v, bn1_g, bn1_b, bn1_m, bn1_v,
        w1, ca_w1, ca_w2, partial, v, cvals, counter);
    k_out<<<B_ * CHUNKS_, 256, 0, stream>>>(a, gw,
        bng_g, bng_b, bng_m, bng_v, v, cvals, (float*)d_out);
}